// Round 4
// baseline (310.157 us; speedup 1.0000x reference)
//
#include <hip/hip_runtime.h>
#include <hip/hip_bf16.h>

#define N 8192
#define D 1024
#define MARGIN 1.0f
#define EPS 1e-6f

typedef __attribute__((ext_vector_type(8))) short bf16x8;
typedef __attribute__((ext_vector_type(4))) float f32x4;
typedef __attribute__((ext_vector_type(8))) _Float16 f16x8;
typedef __attribute__((ext_vector_type(4))) _Float16 f16x4;

__device__ inline unsigned short f2bf(float x) {
    unsigned u = __float_as_uint(x);
    unsigned r = (u + 0x7FFFu + ((u >> 16) & 1u)) >> 16;  // RNE
    return (unsigned short)r;
}

// Kernel 0: fp32 -> bf16 copy + per-row sum of squares.
__global__ __launch_bounds__(256) void prep_kernel(const float* __restrict__ E,
                                                   unsigned short* __restrict__ Ebf,
                                                   float* __restrict__ sq) {
    const int r = blockIdx.x;
    const int tid = threadIdx.x;
    const float4 v = ((const float4*)(E + (size_t)r * D))[tid];
    ushort4 o;
    o.x = f2bf(v.x); o.y = f2bf(v.y); o.z = f2bf(v.z); o.w = f2bf(v.w);
    ((ushort4*)(Ebf + (size_t)r * D))[tid] = o;
    float s = v.x * v.x + v.y * v.y + v.z * v.z + v.w * v.w;
    for (int off = 32; off > 0; off >>= 1) s += __shfl_down(s, off);
    __shared__ float red[4];
    const int lane = tid & 63, wave = tid >> 6;
    if (lane == 0) red[wave] = s;
    __syncthreads();
    if (tid == 0) sq[r] = red[0] + red[1] + red[2] + red[3];
}

// Kernel 1: symmetric D2. Only lower-triangular 128x128 blocks (by >= bx);
// mirror tile written via LDS transpose (Ts aliases the staging buffers).
__global__ __launch_bounds__(256) void gemm_kernel(const unsigned short* __restrict__ E,
                                                   const float* __restrict__ sq,
                                                   _Float16* __restrict__ D2h) {
    __shared__ char smem[128 * 136 * 2];                  // 34816 B
    unsigned short* As = (unsigned short*)smem;           // 8 KB (K-loop)
    unsigned short* Bs = (unsigned short*)(smem + 8192);  // 8 KB (K-loop)
    _Float16* Ts = (_Float16*)smem;                       // 128 x (stride 136) fp16 (epilogue)

    const int tid = threadIdx.x;
    const int lane = tid & 63;
    const int wave = tid >> 6;
    const int wm = wave & 1, wn = wave >> 1;

    // decode linear block id -> (bx, by) with by >= bx
    const int l = blockIdx.x;
    int by = (int)((sqrtf(8.0f * (float)l + 1.0f) - 1.0f) * 0.5f);
    while ((by + 1) * (by + 2) / 2 <= l) ++by;
    while (by * (by + 1) / 2 > l) --by;
    const int bx = l - by * (by + 1) / 2;
    const int rm = by * 128;
    const int cn = bx * 128;

    const int srow = tid >> 2;        // 0..63
    const int scol = (tid & 3) * 8;   // bf16 elements

    const unsigned short* gA = E + (size_t)(rm + srow) * D + scol;
    const unsigned short* gB = E + (size_t)(cn + srow) * D + scol;

    f32x4 acc[4][4] = {};

    const int kq = (lane >> 4) * 8;   // k base within BK=32
    const int mr = lane & 15;

    for (int k0 = 0; k0 < D; k0 += 32) {
        __builtin_amdgcn_global_load_lds(
            (const __attribute__((address_space(1))) unsigned int*)(gA + k0),
            (__attribute__((address_space(3))) unsigned int*)((char*)As + wave * 1024), 16, 0, 0);
        __builtin_amdgcn_global_load_lds(
            (const __attribute__((address_space(1))) unsigned int*)(gA + (size_t)64 * D + k0),
            (__attribute__((address_space(3))) unsigned int*)((char*)As + 4096 + wave * 1024), 16, 0, 0);
        __builtin_amdgcn_global_load_lds(
            (const __attribute__((address_space(1))) unsigned int*)(gB + k0),
            (__attribute__((address_space(3))) unsigned int*)((char*)Bs + wave * 1024), 16, 0, 0);
        __builtin_amdgcn_global_load_lds(
            (const __attribute__((address_space(1))) unsigned int*)(gB + (size_t)64 * D + k0),
            (__attribute__((address_space(3))) unsigned int*)((char*)Bs + 4096 + wave * 1024), 16, 0, 0);
        __syncthreads();

        bf16x8 af[4], bfr[4];
#pragma unroll
        for (int mi = 0; mi < 4; ++mi)
            af[mi] = *(const bf16x8*)(As + (wm * 64 + mi * 16 + mr) * 32 + kq);
#pragma unroll
        for (int ni = 0; ni < 4; ++ni)
            bfr[ni] = *(const bf16x8*)(Bs + (wn * 64 + ni * 16 + mr) * 32 + kq);
#pragma unroll
        for (int mi = 0; mi < 4; ++mi)
#pragma unroll
            for (int ni = 0; ni < 4; ++ni)
                acc[mi][ni] = __builtin_amdgcn_mfma_f32_16x16x32_bf16(af[mi], bfr[ni], acc[mi][ni], 0, 0, 0);
        __syncthreads();
    }

    // C/D layout: col = lane&15, row = (lane>>4)*4 + reg
    const int crow = (lane >> 4) * 4;
    const int ccol = lane & 15;
    const bool offdiag = (bx != by);
    float sqj[4];
#pragma unroll
    for (int ni = 0; ni < 4; ++ni)
        sqj[ni] = sq[cn + wn * 64 + ni * 16 + ccol];
#pragma unroll
    for (int mi = 0; mi < 4; ++mi) {
        const int lrow = wm * 64 + mi * 16 + crow;   // tile-local row base
        const int i0 = rm + lrow;
        float sqi[4];
#pragma unroll
        for (int r = 0; r < 4; ++r) sqi[r] = sq[i0 + r];
#pragma unroll
        for (int ni = 0; ni < 4; ++ni) {
            const int lcol = wn * 64 + ni * 16 + ccol;  // tile-local col
            const int j = cn + lcol;
            f16x4 tv;
#pragma unroll
            for (int r = 0; r < 4; ++r) {
                float d2 = fmaxf(sqi[r] + sqj[ni] - 2.0f * acc[mi][ni][r], 0.0f);
                _Float16 h = (_Float16)d2;
                D2h[(size_t)(i0 + r) * N + j] = h;
                tv[r] = h;
            }
            if (offdiag)
                *(f16x4*)(Ts + (size_t)lcol * 136 + lrow) = tv;  // transposed stage
        }
    }
    if (offdiag) {
        __syncthreads();
        // coalesced mirror store: row rt of mirror tile = column rt of direct tile
#pragma unroll
        for (int it = 0; it < 8; ++it) {
            const int rt = it * 16 + (tid >> 4);
            const int seg = tid & 15;
            f16x8 v = *(const f16x8*)(Ts + (size_t)rt * 136 + seg * 8);
            *(f16x8*)(D2h + (size_t)(cn + rt) * N + rm + seg * 8) = v;
        }
    }
}

// Kernel 2: one WAVE per anchor row. Mining + fused exact-fp32 loss.
// Numerics identical to round 3: same u64 packing, same tie-breaks, fp32 compares.
__global__ __launch_bounds__(256) void mine_kernel(const _Float16* __restrict__ D2h,
                                                   const int* __restrict__ target,
                                                   const float* __restrict__ E,
                                                   float* __restrict__ loss_arr) {
    __shared__ unsigned char cls[N];  // 8 KB: class id per sample (fits: N_CLASSES=128)
    const int tid = threadIdx.x;
    const int lane = tid & 63, wave = tid >> 6;
    for (int k = tid; k < N / 4; k += 256) {
        int4 t4 = ((const int4*)target)[k];
        uchar4 c4;
        c4.x = (unsigned char)t4.x; c4.y = (unsigned char)t4.y;
        c4.z = (unsigned char)t4.z; c4.w = (unsigned char)t4.w;
        ((uchar4*)cls)[k] = c4;
    }
    __syncthreads();

    const int i = blockIdx.x * 4 + wave;   // this wave's anchor row
    const unsigned char tc = cls[i];
    const _Float16* row = D2h + (size_t)i * N;

    // Pass 1: load row into registers (16 x f16x8 = 128 elems/lane), build
    // same-class bitmask, reduce hardest-positive (max) and hardest-negative (min).
    f16x8 rv[16];
#pragma unroll
    for (int it = 0; it < 16; ++it)
        rv[it] = *(const f16x8*)(row + it * 512 + lane * 8);

    unsigned long long pmax = 0ull;   // packed (fp32 d2 bits, idx): max over positives
    unsigned long long nmin = ~0ull;  // min over negatives
    unsigned long long same[2] = {0ull, 0ull};
#pragma unroll
    for (int it = 0; it < 16; ++it) {
        const int jb = it * 512 + lane * 8;
        const unsigned long long c8 = *(const unsigned long long*)(cls + jb);
#pragma unroll
        for (int e = 0; e < 8; ++e) {
            const int j = jb + e;
            const bool s = ((unsigned char)(c8 >> (8 * e))) == tc;
            float d2 = (float)rv[it][e];
            unsigned long long pk = ((unsigned long long)__float_as_uint(d2) << 32) | (unsigned)j;
            if (s) {
                same[it >> 3] |= 1ull << (((it & 7) << 3) | e);
                if (j != i && pk > pmax) pmax = pk;
            } else if (pk < nmin) {
                nmin = pk;
            }
        }
    }
    for (int off = 1; off < 64; off <<= 1) {
        unsigned long long t1 = __shfl_xor(pmax, off); if (t1 > pmax) pmax = t1;
        unsigned long long t2 = __shfl_xor(nmin, off); if (t2 < nmin) nmin = t2;
    }
    const float lo = __uint_as_float((unsigned)(pmax >> 32));   // dp^2
    const float hh = sqrtf(lo) + MARGIN;
    const float hi = hh * hh;

    // Pass 2: semi-hard window from the register stash (no memory traffic).
    unsigned long long smin = ~0ull;
#pragma unroll
    for (int it = 0; it < 16; ++it) {
        const int jb = it * 512 + lane * 8;
#pragma unroll
        for (int e = 0; e < 8; ++e) {
            if (!((same[it >> 3] >> (((it & 7) << 3) | e)) & 1ull)) {
                float d2 = (float)rv[it][e];
                if (d2 > lo && d2 < hi) {
                    const int j = jb + e;
                    unsigned long long pk = ((unsigned long long)__float_as_uint(d2) << 32) | (unsigned)j;
                    if (pk < smin) smin = pk;
                }
            }
        }
    }
    for (int off = 1; off < 64; off <<= 1) {
        unsigned long long t2 = __shfl_xor(smin, off); if (t2 < smin) smin = t2;
    }
    const int pi = (int)(unsigned)(pmax & 0xFFFFFFFFu);
    const int ni = (smin != ~0ull) ? (int)(unsigned)(smin & 0xFFFFFFFFu)
                                   : (int)(unsigned)(nmin & 0xFFFFFFFFu);

    // Fused loss: exact fp32 dp/dn (reference +EPS semantics), wave-parallel over D.
    const float4* Ea = (const float4*)(E + (size_t)i * D);
    const float4* Ep = (const float4*)(E + (size_t)pi * D);
    const float4* En = (const float4*)(E + (size_t)ni * D);
    float s1 = 0.0f, s2 = 0.0f;
#pragma unroll
    for (int c = 0; c < 4; ++c) {
        const int idx = c * 64 + lane;
        const float4 a = Ea[idx];
        const float4 p = Ep[idx];
        const float4 n = En[idx];
        float t;
        t = a.x - p.x + EPS; s1 += t * t;
        t = a.y - p.y + EPS; s1 += t * t;
        t = a.z - p.z + EPS; s1 += t * t;
        t = a.w - p.w + EPS; s1 += t * t;
        t = a.x - n.x + EPS; s2 += t * t;
        t = a.y - n.y + EPS; s2 += t * t;
        t = a.z - n.z + EPS; s2 += t * t;
        t = a.w - n.w + EPS; s2 += t * t;
    }
    for (int off = 1; off < 64; off <<= 1) {
        s1 += __shfl_xor(s1, off);
        s2 += __shfl_xor(s2, off);
    }
    if (lane == 0)
        loss_arr[i] = fmaxf(sqrtf(s1) - sqrtf(s2) + MARGIN, 0.0f);
}

// Kernel 3: mean over 8192 per-anchor losses (single block; no global atomics).
__global__ __launch_bounds__(256) void reduce_kernel(const float* __restrict__ loss_arr,
                                                     float* __restrict__ out) {
    const int tid = threadIdx.x;
    float s = 0.0f;
    for (int k = tid; k < N; k += 256) s += loss_arr[k];
    for (int off = 32; off > 0; off >>= 1) s += __shfl_down(s, off);
    __shared__ float red[4];
    const int lane = tid & 63, wave = tid >> 6;
    if (lane == 0) red[wave] = s;
    __syncthreads();
    if (tid == 0) out[0] = (red[0] + red[1] + red[2] + red[3]) * (1.0f / N);
}

extern "C" void kernel_launch(void* const* d_in, const int* in_sizes, int n_in,
                              void* d_out, int out_size, void* d_ws, size_t ws_size,
                              hipStream_t stream) {
    const float* E = (const float*)d_in[0];
    const int* target = (const int*)d_in[1];
    float* out = (float*)d_out;
    char* ws = (char*)d_ws;

    // Workspace layout (~144.1 MB):
    unsigned short* Ebf = (unsigned short*)ws;                         // 16 MB
    float* sq = (float*)(ws + (size_t)16777216);                       // 32 KB
    float* loss_arr = (float*)(ws + (size_t)16777216 + 32768);         // 32 KB
    _Float16* D2h = (_Float16*)(ws + (size_t)16875520);                // 128 MB

    prep_kernel<<<N, 256, 0, stream>>>(E, Ebf, sq);
    gemm_kernel<<<2080, 256, 0, stream>>>(Ebf, sq, D2h);  // 64*65/2 lower-tri blocks
    mine_kernel<<<N / 4, 256, 0, stream>>>(D2h, target, E, loss_arr);
    reduce_kernel<<<1, 256, 0, stream>>>(loss_arr, out);
}

// Round 5
// 240.372 us; speedup vs baseline: 1.2903x; 1.2903x over previous
//
#include <hip/hip_runtime.h>
#include <hip/hip_bf16.h>

#define N 8192
#define D 1024
#define MARGIN 1.0f
#define EPS 1e-6f

typedef __attribute__((ext_vector_type(8))) short bf16x8;
typedef __attribute__((ext_vector_type(4))) float f32x4;
typedef __attribute__((ext_vector_type(8))) _Float16 f16x8;
typedef __attribute__((ext_vector_type(4))) _Float16 f16x4;

__device__ inline unsigned short f2bf(float x) {
    unsigned u = __float_as_uint(x);
    unsigned r = (u + 0x7FFFu + ((u >> 16) & 1u)) >> 16;  // RNE
    return (unsigned short)r;
}

// Kernel 0: fp32 -> bf16 copy + per-row sum of squares.
__global__ __launch_bounds__(256) void prep_kernel(const float* __restrict__ E,
                                                   unsigned short* __restrict__ Ebf,
                                                   float* __restrict__ sq) {
    const int r = blockIdx.x;
    const int tid = threadIdx.x;
    const float4 v = ((const float4*)(E + (size_t)r * D))[tid];
    ushort4 o;
    o.x = f2bf(v.x); o.y = f2bf(v.y); o.z = f2bf(v.z); o.w = f2bf(v.w);
    ((ushort4*)(Ebf + (size_t)r * D))[tid] = o;
    float s = v.x * v.x + v.y * v.y + v.z * v.z + v.w * v.w;
    for (int off = 32; off > 0; off >>= 1) s += __shfl_down(s, off);
    __shared__ float red[4];
    const int lane = tid & 63, wave = tid >> 6;
    if (lane == 0) red[wave] = s;
    __syncthreads();
    if (tid == 0) sq[r] = red[0] + red[1] + red[2] + red[3];
}

// Kernel 0b: target int32 -> uchar class ids (N_CLASSES=128 fits).
__global__ __launch_bounds__(256) void cls_kernel(const int* __restrict__ target,
                                                  unsigned char* __restrict__ cls) {
    const int t = blockIdx.x * 256 + threadIdx.x;  // 32 blocks x 256 = 8192
    cls[t] = (unsigned char)target[t];
}

// Kernel 1: symmetric D2. Only lower-triangular 128x128 blocks (by >= bx);
// mirror tile written via LDS transpose (Ts aliases the staging buffers).
__global__ __launch_bounds__(256) void gemm_kernel(const unsigned short* __restrict__ E,
                                                   const float* __restrict__ sq,
                                                   _Float16* __restrict__ D2h) {
    __shared__ char smem[128 * 136 * 2];                  // 34816 B
    unsigned short* As = (unsigned short*)smem;           // 8 KB (K-loop)
    unsigned short* Bs = (unsigned short*)(smem + 8192);  // 8 KB (K-loop)
    _Float16* Ts = (_Float16*)smem;                       // 128 x (stride 136) fp16 (epilogue)

    const int tid = threadIdx.x;
    const int lane = tid & 63;
    const int wave = tid >> 6;
    const int wm = wave & 1, wn = wave >> 1;

    // decode linear block id -> (bx, by) with by >= bx
    const int l = blockIdx.x;
    int by = (int)((sqrtf(8.0f * (float)l + 1.0f) - 1.0f) * 0.5f);
    while ((by + 1) * (by + 2) / 2 <= l) ++by;
    while (by * (by + 1) / 2 > l) --by;
    const int bx = l - by * (by + 1) / 2;
    const int rm = by * 128;
    const int cn = bx * 128;

    const int srow = tid >> 2;        // 0..63
    const int scol = (tid & 3) * 8;   // bf16 elements

    const unsigned short* gA = E + (size_t)(rm + srow) * D + scol;
    const unsigned short* gB = E + (size_t)(cn + srow) * D + scol;

    f32x4 acc[4][4] = {};

    const int kq = (lane >> 4) * 8;   // k base within BK=32
    const int mr = lane & 15;

    for (int k0 = 0; k0 < D; k0 += 32) {
        __builtin_amdgcn_global_load_lds(
            (const __attribute__((address_space(1))) unsigned int*)(gA + k0),
            (__attribute__((address_space(3))) unsigned int*)((char*)As + wave * 1024), 16, 0, 0);
        __builtin_amdgcn_global_load_lds(
            (const __attribute__((address_space(1))) unsigned int*)(gA + (size_t)64 * D + k0),
            (__attribute__((address_space(3))) unsigned int*)((char*)As + 4096 + wave * 1024), 16, 0, 0);
        __builtin_amdgcn_global_load_lds(
            (const __attribute__((address_space(1))) unsigned int*)(gB + k0),
            (__attribute__((address_space(3))) unsigned int*)((char*)Bs + wave * 1024), 16, 0, 0);
        __builtin_amdgcn_global_load_lds(
            (const __attribute__((address_space(1))) unsigned int*)(gB + (size_t)64 * D + k0),
            (__attribute__((address_space(3))) unsigned int*)((char*)Bs + 4096 + wave * 1024), 16, 0, 0);
        __syncthreads();

        bf16x8 af[4], bfr[4];
#pragma unroll
        for (int mi = 0; mi < 4; ++mi)
            af[mi] = *(const bf16x8*)(As + (wm * 64 + mi * 16 + mr) * 32 + kq);
#pragma unroll
        for (int ni = 0; ni < 4; ++ni)
            bfr[ni] = *(const bf16x8*)(Bs + (wn * 64 + ni * 16 + mr) * 32 + kq);
#pragma unroll
        for (int mi = 0; mi < 4; ++mi)
#pragma unroll
            for (int ni = 0; ni < 4; ++ni)
                acc[mi][ni] = __builtin_amdgcn_mfma_f32_16x16x32_bf16(af[mi], bfr[ni], acc[mi][ni], 0, 0, 0);
        __syncthreads();
    }

    // C/D layout: col = lane&15, row = (lane>>4)*4 + reg
    const int crow = (lane >> 4) * 4;
    const int ccol = lane & 15;
    const bool offdiag = (bx != by);
    float sqj[4];
#pragma unroll
    for (int ni = 0; ni < 4; ++ni)
        sqj[ni] = sq[cn + wn * 64 + ni * 16 + ccol];
#pragma unroll
    for (int mi = 0; mi < 4; ++mi) {
        const int lrow = wm * 64 + mi * 16 + crow;   // tile-local row base
        const int i0 = rm + lrow;
        float sqi[4];
#pragma unroll
        for (int r = 0; r < 4; ++r) sqi[r] = sq[i0 + r];
#pragma unroll
        for (int ni = 0; ni < 4; ++ni) {
            const int lcol = wn * 64 + ni * 16 + ccol;  // tile-local col
            const int j = cn + lcol;
            f16x4 tv;
#pragma unroll
            for (int r = 0; r < 4; ++r) {
                float d2 = fmaxf(sqi[r] + sqj[ni] - 2.0f * acc[mi][ni][r], 0.0f);
                _Float16 h = (_Float16)d2;
                D2h[(size_t)(i0 + r) * N + j] = h;
                tv[r] = h;
            }
            if (offdiag)
                *(f16x4*)(Ts + (size_t)lcol * 136 + lrow) = tv;  // transposed stage
        }
    }
    if (offdiag) {
        __syncthreads();
        // coalesced mirror store: row rt of mirror tile = column rt of direct tile
#pragma unroll
        for (int it = 0; it < 8; ++it) {
            const int rt = it * 16 + (tid >> 4);
            const int seg = tid & 15;
            f16x8 v = *(const f16x8*)(Ts + (size_t)rt * 136 + seg * 8);
            *(f16x8*)(D2h + (size_t)(cn + rt) * N + rm + seg * 8) = v;
        }
    }
}

// Kernel 2: one WAVE per anchor row, NO register stash (pass 2 re-reads, L2-hot).
// Pass 2 needs no class test: lo = max positive d2, window requires d2 > lo strictly,
// so all positives (and self) are excluded by the window alone.
// Selection semantics identical to round 3/4: same u64 packing, tie-breaks, fp32 compares.
__global__ __launch_bounds__(256) void mine_kernel(const _Float16* __restrict__ D2h,
                                                   const unsigned char* __restrict__ cls,
                                                   const float* __restrict__ E,
                                                   float* __restrict__ loss_arr) {
    __shared__ unsigned char cls_s[N];  // 8 KB
    const int tid = threadIdx.x;
    const int lane = tid & 63, wave = tid >> 6;
    for (int k = tid; k < N / 16; k += 256)
        ((int4*)cls_s)[k] = ((const int4*)cls)[k];
    __syncthreads();

    const int i = blockIdx.x * 4 + wave;   // this wave's anchor row
    const unsigned char tc = cls_s[i];
    const _Float16* row = D2h + (size_t)i * N;

    // Pass 1: hardest positive (max, same-class, j!=i) and hardest negative (min, diff-class).
    unsigned long long pmax = 0ull;
    unsigned long long nmin = ~0ull;
    for (int it = 0; it < 16; ++it) {
        const int jb = it * 512 + lane * 8;
        const f16x8 v = *(const f16x8*)(row + jb);
        const unsigned long long c8 = *(const unsigned long long*)(cls_s + jb);
#pragma unroll
        for (int e = 0; e < 8; ++e) {
            const int j = jb + e;
            const float d2 = (float)v[e];
            const unsigned long long pk = ((unsigned long long)__float_as_uint(d2) << 32) | (unsigned)j;
            if (((unsigned char)(c8 >> (8 * e))) == tc) {
                if (j != i && pk > pmax) pmax = pk;
            } else if (pk < nmin) {
                nmin = pk;
            }
        }
    }
    for (int off = 1; off < 64; off <<= 1) {
        unsigned long long t1 = __shfl_xor(pmax, off); if (t1 > pmax) pmax = t1;
        unsigned long long t2 = __shfl_xor(nmin, off); if (t2 < nmin) nmin = t2;
    }
    const float lo = __uint_as_float((unsigned)(pmax >> 32));   // dp^2
    const float hh = sqrtf(lo) + MARGIN;
    const float hi = hh * hh;

    // Pass 2: semi-hard window, class-test-free (see note above). Row re-read is L2-hot.
    unsigned long long smin = ~0ull;
    for (int it = 0; it < 16; ++it) {
        const int jb = it * 512 + lane * 8;
        const f16x8 v = *(const f16x8*)(row + jb);
#pragma unroll
        for (int e = 0; e < 8; ++e) {
            const float d2 = (float)v[e];
            if (d2 > lo && d2 < hi) {
                const int j = jb + e;
                const unsigned long long pk = ((unsigned long long)__float_as_uint(d2) << 32) | (unsigned)j;
                if (pk < smin) smin = pk;
            }
        }
    }
    for (int off = 1; off < 64; off <<= 1) {
        unsigned long long t2 = __shfl_xor(smin, off); if (t2 < smin) smin = t2;
    }
    const int pi = (int)(unsigned)(pmax & 0xFFFFFFFFu);
    const int ni = (smin != ~0ull) ? (int)(unsigned)(smin & 0xFFFFFFFFu)
                                   : (int)(unsigned)(nmin & 0xFFFFFFFFu);

    // Fused loss: exact fp32 dp/dn (reference +EPS semantics), wave-parallel over D.
    const float4* Ea = (const float4*)(E + (size_t)i * D);
    const float4* Ep = (const float4*)(E + (size_t)pi * D);
    const float4* En = (const float4*)(E + (size_t)ni * D);
    float s1 = 0.0f, s2 = 0.0f;
#pragma unroll
    for (int c = 0; c < 4; ++c) {
        const int idx = c * 64 + lane;
        const float4 a = Ea[idx];
        const float4 p = Ep[idx];
        const float4 n = En[idx];
        float t;
        t = a.x - p.x + EPS; s1 += t * t;
        t = a.y - p.y + EPS; s1 += t * t;
        t = a.z - p.z + EPS; s1 += t * t;
        t = a.w - p.w + EPS; s1 += t * t;
        t = a.x - n.x + EPS; s2 += t * t;
        t = a.y - n.y + EPS; s2 += t * t;
        t = a.z - n.z + EPS; s2 += t * t;
        t = a.w - n.w + EPS; s2 += t * t;
    }
    for (int off = 1; off < 64; off <<= 1) {
        s1 += __shfl_xor(s1, off);
        s2 += __shfl_xor(s2, off);
    }
    if (lane == 0)
        loss_arr[i] = fmaxf(sqrtf(s1) - sqrtf(s2) + MARGIN, 0.0f);
}

// Kernel 3: mean over 8192 per-anchor losses (single block; no global atomics).
__global__ __launch_bounds__(256) void reduce_kernel(const float* __restrict__ loss_arr,
                                                     float* __restrict__ out) {
    const int tid = threadIdx.x;
    float s = 0.0f;
    for (int k = tid; k < N; k += 256) s += loss_arr[k];
    for (int off = 32; off > 0; off >>= 1) s += __shfl_down(s, off);
    __shared__ float red[4];
    const int lane = tid & 63, wave = tid >> 6;
    if (lane == 0) red[wave] = s;
    __syncthreads();
    if (tid == 0) out[0] = (red[0] + red[1] + red[2] + red[3]) * (1.0f / N);
}

extern "C" void kernel_launch(void* const* d_in, const int* in_sizes, int n_in,
                              void* d_out, int out_size, void* d_ws, size_t ws_size,
                              hipStream_t stream) {
    const float* E = (const float*)d_in[0];
    const int* target = (const int*)d_in[1];
    float* out = (float*)d_out;
    char* ws = (char*)d_ws;

    // Workspace layout (~144.1 MB):
    unsigned short* Ebf = (unsigned short*)ws;                         // 16 MB
    float* sq = (float*)(ws + (size_t)16777216);                       // 32 KB
    float* loss_arr = (float*)(ws + (size_t)16777216 + 32768);         // 32 KB
    unsigned char* cls = (unsigned char*)(ws + (size_t)16777216 + 65536); // 8 KB
    _Float16* D2h = (_Float16*)(ws + (size_t)16875520);                // 128 MB

    prep_kernel<<<N, 256, 0, stream>>>(E, Ebf, sq);
    cls_kernel<<<N / 256, 256, 0, stream>>>(target, cls);
    gemm_kernel<<<2080, 256, 0, stream>>>(Ebf, sq, D2h);  // 64*65/2 lower-tri blocks
    mine_kernel<<<N / 4, 256, 0, stream>>>(D2h, cls, E, loss_arr);
    reduce_kernel<<<1, 256, 0, stream>>>(loss_arr, out);
}